// Round 16
// baseline (49.777 us; speedup 1.0000x reference)
//
#include <hip/hip_runtime.h>
#include <hip/hip_bf16.h>

// Problem constants (B, T, C, HS) from the reference.
#define NB 256
#define NT 256
#define NC 384
#define NH 64
#define NW 192              // 3 * NH concatenated output cols
#define WT_ELEMS (NW * NC)  // Wt2 bf16 elements = 73728 (147456 B)

typedef short bf16x8 __attribute__((ext_vector_type(8)));
typedef float f32x4 __attribute__((ext_vector_type(4)));

__device__ __forceinline__ unsigned short f2bf(float f) {
  union { float f; unsigned int i; } c;
  c.f = f;
  const unsigned int r = c.i + 0x7fffu + ((c.i >> 16) & 1u);
  return (unsigned short)(r >> 16);
}

__device__ __forceinline__ unsigned short f2bf_hw(float f) {
  __hip_bfloat16 b = __float2bfloat16(f);
  return *reinterpret_cast<unsigned short*>(&b);
}

__device__ __forceinline__ bf16x8 cvt8(float4 lo, float4 hi) {
  union { bf16x8 v; unsigned short u[8]; } au;
  au.u[0] = f2bf_hw(lo.x); au.u[1] = f2bf_hw(lo.y);
  au.u[2] = f2bf_hw(lo.z); au.u[3] = f2bf_hw(lo.w);
  au.u[4] = f2bf_hw(hi.x); au.u[5] = f2bf_hw(hi.y);
  au.u[6] = f2bf_hw(hi.z); au.u[7] = f2bf_hw(hi.w);
  return au.v;
}

// ---------------------------------------------------------------------------
// Kernel 0: build FRAGMENT-MAJOR weights (unchanged since round 11).
// Wt2[((kt*12 + ni)*64 + lane)*8 + j] = W_sel[k][h]:
//   n = ni*16 + (lane&15), k = kt*32 + (lane>>4)*8 + j.
// ---------------------------------------------------------------------------
__global__ __launch_bounds__(256) void w_prep_kernel(
    const float* __restrict__ Wq,
    const float* __restrict__ Wk,
    const float* __restrict__ Wv,
    unsigned short* __restrict__ Wt2) {
  const int o = blockIdx.x * 256 + threadIdx.x;
  if (o >= WT_ELEMS) return;
  const int j = o & 7;
  const int lane = (o >> 3) & 63;
  const int fi = o >> 9;  // kt*12 + ni
  const int ni = fi % 12;
  const int kt = fi / 12;
  const int n = ni * 16 + (lane & 15);
  const int k = kt * 32 + ((lane >> 4) << 3) + j;
  const float* W = (n < 64) ? Wq : (n < 128) ? Wk : Wv;
  Wt2[o] = f2bf(W[k * NH + (n & 63)]);
}

// ---------------------------------------------------------------------------
// Kernel 1 (round 16): fused proj+attn — the CLEAN LDS-traffic test.
//
// Round-15 post-mortem: the 32x96 tile test was confounded (prefetch depth
// cut 3->2 alongside the W-read halving) and regressed. This round is
// round 14 VERBATIM with exactly one variable changed: wave proj tile
// 16x192 -> 32x96 (rg = w>>1, ch = w&1), KEEPING the 3-deep A/B/C register
// pipeline (4 float4/set). Per-CU LDS W-traffic halves (2.25 -> 1.15 MB,
// the ~9-11 us serial term); x-row duplication across wave pairs is
// L1-served (4 KB slice per tile, 32 KB L1).
//
// Proj: W fragment-major resident in LDS (staged once, 9 DMA/thread);
// x direct-to-reg 3-deep named sets; no barriers in the k-loop.
// Attn: byte-identical to rounds 14/15 (verified): 16-wave pandiagonal
// magic q-tile map, 16-row tiles, parity diagonal mask.
// LDS reuse after proj: Kls 32K | Vtls 32K | Qls 32K | Pls 16x640B.
// mfma_f32_16x16x32_bf16 layouts (HW-verified round 2):
//   A/B: k = (l>>4)*8+j contiguous;  D: n = l&15, m = (l>>4)*4 + r.
// ---------------------------------------------------------------------------
__global__ __launch_bounds__(1024, 4) void fused_qkv_attn_kernel(
    const float* __restrict__ x,
    const unsigned short* __restrict__ Wt2,
    float* __restrict__ out) {
  __shared__ __align__(16) unsigned char lds[147456];

  const int tid = threadIdx.x;
  const int w = tid >> 6;  // 0..15
  const int lane = tid & 63;
  const int l15 = lane & 15;
  const int lg = lane >> 4;
  const int b = blockIdx.x;
  const int row0 = b * NT;
  const int rg = w >> 1;  // proj row-group 0..7 (32 rows)
  const int ch = w & 1;   // proj col-half 0..1 (96 cols = 6 ni)

  f32x4 acc[2][6];
#pragma unroll
  for (int mi = 0; mi < 2; ++mi)
#pragma unroll
    for (int ni = 0; ni < 6; ++ni)
#pragma unroll
      for (int r = 0; r < 4; ++r) acc[mi][ni][r] = 0.f;

  // ---- stage ALL of W into LDS (9 x 16B DMA per thread, linear) ----
#pragma unroll
  for (int i = 0; i < 9; ++i) {
    const int idx = i * 1024 + tid;  // 16B chunk index, 9216 total
    __builtin_amdgcn_global_load_lds(
        (const __attribute__((address_space(1))) void*)(Wt2 + idx * 8),
        (__attribute__((address_space(3))) void*)(lds + idx * 16), 16, 0, 0);
  }

  // ---- A-pipeline prologue: tiles 0,1,2 into named 3-deep sets ----
  const float* xa0 = x + (size_t)(row0 + rg * 32 + l15) * NC + lg * 8;
  const float* xa1 = xa0 + (size_t)16 * NC;

  float4 aA0, aA1, aA2, aA3, aB0, aB1, aB2, aB3, aC0, aC1, aC2, aC3;

#define LOADA(S, KT)                                                          \
  do {                                                                        \
    a##S##0 = *reinterpret_cast<const float4*>(xa0 + (KT)*32);                \
    a##S##1 = *reinterpret_cast<const float4*>(xa0 + (KT)*32 + 4);            \
    a##S##2 = *reinterpret_cast<const float4*>(xa1 + (KT)*32);                \
    a##S##3 = *reinterpret_cast<const float4*>(xa1 + (KT)*32 + 4);            \
  } while (0)

  LOADA(A, 0);
  LOADA(B, 1);
  LOADA(C, 2);

  // Drain once (prologue only): W image + first x tiles resident.
  asm volatile("s_waitcnt vmcnt(0)" ::: "memory");
  __builtin_amdgcn_s_barrier();

  // ---- proj loop: consume set, refill 3 ahead; W from LDS ----
  const unsigned short* Wl =
      reinterpret_cast<const unsigned short*>(lds) + lane * 8;

#define STEP(S, KT)                                                          \
  do {                                                                       \
    const bf16x8 afr0 = cvt8(a##S##0, a##S##1);                              \
    const bf16x8 afr1 = cvt8(a##S##2, a##S##3);                              \
    if ((KT) + 3 < 12) LOADA(S, (KT) + 3);                                   \
    _Pragma("unroll") for (int ni = 0; ni < 6; ++ni) {                       \
      const bf16x8 bfr = *reinterpret_cast<const bf16x8*>(                   \
          Wl + (size_t)((KT)*12 + ch * 6 + ni) * 512);                       \
      acc[0][ni] = __builtin_amdgcn_mfma_f32_16x16x32_bf16(                  \
          afr0, bfr, acc[0][ni], 0, 0, 0);                                   \
      acc[1][ni] = __builtin_amdgcn_mfma_f32_16x16x32_bf16(                  \
          afr1, bfr, acc[1][ni], 0, 0, 0);                                   \
    }                                                                        \
  } while (0)

  STEP(A, 0);  STEP(B, 1);  STEP(C, 2);
  STEP(A, 3);  STEP(B, 4);  STEP(C, 5);
  STEP(A, 6);  STEP(B, 7);  STEP(C, 8);
  STEP(A, 9);  STEP(B, 10); STEP(C, 11);

  // All waves done reading the W image before overwriting LDS with K/V/Q.
  __syncthreads();

  // ---- epilogue: scatter acc into attention LDS layouts (bf16) ----
  unsigned short* Kls = reinterpret_cast<unsigned short*>(lds);           // 32K
  unsigned short* Vtls = reinterpret_cast<unsigned short*>(lds + 32768);  // 32K
  unsigned short* Qls = reinterpret_cast<unsigned short*>(lds + 65536);   // 32K
  unsigned short* Pls = reinterpret_cast<unsigned short*>(lds + 98304);   // 20K

#pragma unroll
  for (int mi = 0; mi < 2; ++mi)
#pragma unroll
    for (int ni = 0; ni < 6; ++ni) {
      const int n = ch * 96 + ni * 16 + l15;
#pragma unroll
      for (int r = 0; r < 4; ++r) {
        const int srow = rg * 32 + mi * 16 + lg * 4 + r;
        const unsigned short val = f2bf_hw(acc[mi][ni][r]);
        if (n < 64) {
          Qls[srow * 64 + (n ^ ((srow & 7) << 3))] = val;
        } else if (n < 128) {
          const int h = n - 64;
          Kls[srow * 64 + (h ^ ((srow & 7) << 3))] = val;
        } else {
          const int h = n - 128;
          Vtls[h * 256 + (srow ^ ((h & 7) << 3))] = val;
        }
      }
    }
  __syncthreads();

  // ---- attention phase (byte-identical to rounds 14/15, verified) ----
  const int qt = (int)((0x583E2F49C1A7B6D0ull >> (w << 2)) & 15ull);
  const int wbase = qt * 16;

  bf16x8 a_q[2];
#pragma unroll
  for (int ks = 0; ks < 2; ++ks) {
    const int srow = wbase + l15;
    a_q[ks] = *reinterpret_cast<const bf16x8*>(
        Qls + srow * 64 + ((ks * 32 + lg * 8) ^ ((srow & 7) << 3)));
  }

  f32x4 o[4];
  float mrun[4], lrun[4];
#pragma unroll
  for (int r = 0; r < 4; ++r) {
    mrun[r] = -3.0e38f;
    lrun[r] = 0.f;
#pragma unroll
    for (int hi = 0; hi < 4; ++hi) o[hi][r] = 0.f;
  }

  unsigned short* Pw = Pls + w * 640;  // per-wave [16][40]
  const int njmax = qt >> 1;

  for (int j = 0; j <= njmax; ++j) {
    f32x4 s_acc[2];
#pragma unroll
    for (int si = 0; si < 2; ++si)
#pragma unroll
      for (int r = 0; r < 4; ++r) s_acc[si][r] = 0.f;

#pragma unroll
    for (int ks = 0; ks < 2; ++ks) {
      bf16x8 bk[2];
#pragma unroll
      for (int si = 0; si < 2; ++si) {
        const int srow = j * 32 + si * 16 + l15;
        const int kel = ks * 32 + lg * 8;
        bk[si] = *reinterpret_cast<const bf16x8*>(
            Kls + srow * 64 + (kel ^ ((srow & 7) << 3)));
      }
#pragma unroll
      for (int si = 0; si < 2; ++si)
        s_acc[si] = __builtin_amdgcn_mfma_f32_16x16x32_bf16(
            a_q[ks], bk[si], s_acc[si], 0, 0, 0);
    }

    const bool dlast = (j == njmax);
#pragma unroll
    for (int r = 0; r < 4; ++r) {
      const int mloc = lg * 4 + r;
      float v0 = s_acc[0][r] * 0.125f;
      float v1 = s_acc[1][r] * 0.125f;
      if (dlast) {
        if ((qt & 1) == 0) {
          if (l15 > mloc) v0 = -3.0e38f;
          v1 = -3.0e38f;  // whole upper half-block is future
        } else {
          if (l15 > mloc) v1 = -3.0e38f;
        }
      }
      float pm = fmaxf(v0, v1);
      pm = fmaxf(pm, __shfl_xor(pm, 1, 16));
      pm = fmaxf(pm, __shfl_xor(pm, 2, 16));
      pm = fmaxf(pm, __shfl_xor(pm, 4, 16));
      pm = fmaxf(pm, __shfl_xor(pm, 8, 16));
      const float mnew = fmaxf(mrun[r], pm);
      const float alpha = __expf(mrun[r] - mnew);
      mrun[r] = mnew;
      const float p0 = __expf(v0 - mnew);
      const float p1 = __expf(v1 - mnew);
      float ps = p0 + p1;
      ps += __shfl_xor(ps, 1, 16);
      ps += __shfl_xor(ps, 2, 16);
      ps += __shfl_xor(ps, 4, 16);
      ps += __shfl_xor(ps, 8, 16);
      lrun[r] = lrun[r] * alpha + ps;
#pragma unroll
      for (int hi = 0; hi < 4; ++hi) o[hi][r] *= alpha;
      Pw[mloc * 40 + l15] = f2bf(p0);
      Pw[mloc * 40 + 16 + l15] = f2bf(p1);
    }

    const bf16x8 pa =
        *reinterpret_cast<const bf16x8*>(Pw + l15 * 40 + lg * 8);
#pragma unroll
    for (int hi = 0; hi < 4; ++hi) {
      const int h = hi * 16 + l15;
      const int sel = j * 32 + lg * 8;
      const bf16x8 bv = *reinterpret_cast<const bf16x8*>(
          Vtls + h * 256 + (sel ^ ((h & 7) << 3)));
      o[hi] = __builtin_amdgcn_mfma_f32_16x16x32_bf16(pa, bv, o[hi], 0, 0, 0);
    }
  }

  // ---- out store ----
  float* og = out + ((size_t)b * NT + wbase) * NH;
#pragma unroll
  for (int r = 0; r < 4; ++r) {
    const float inv = 1.f / lrun[r];
    const int m = lg * 4 + r;
#pragma unroll
    for (int hi = 0; hi < 4; ++hi)
      og[m * 64 + hi * 16 + l15] = o[hi][r] * inv;
  }
}

// ---------------------------------------------------------------------------
extern "C" void kernel_launch(void* const* d_in, const int* in_sizes, int n_in,
                              void* d_out, int out_size, void* d_ws,
                              size_t ws_size, hipStream_t stream) {
  const float* x  = (const float*)d_in[0];
  const float* Wq = (const float*)d_in[1];
  const float* Wk = (const float*)d_in[2];
  const float* Wv = (const float*)d_in[3];
  unsigned short* Wt2 = (unsigned short*)d_ws;  // 147 KB, fragment-major
  float* out = (float*)d_out;

  w_prep_kernel<<<dim3((WT_ELEMS + 255) / 256), dim3(256), 0, stream>>>(
      Wq, Wk, Wv, Wt2);
  fused_qkv_attn_kernel<<<dim3(NB), dim3(1024), 0, stream>>>(x, Wt2, out);
}

// Round 17
// 40.972 us; speedup vs baseline: 1.2149x; 1.2149x over previous
//
#include <hip/hip_runtime.h>
#include <hip/hip_bf16.h>

// Problem constants (B, T, C, HS) from the reference.
#define NB 256
#define NT 256
#define NC 384
#define NH 64
#define NW 192              // 3 * NH concatenated output cols
#define WT_ELEMS (NW * NC)  // Wt2 bf16 elements = 73728 (147456 B)

typedef short bf16x8 __attribute__((ext_vector_type(8)));
typedef float f32x4 __attribute__((ext_vector_type(4)));

__device__ __forceinline__ unsigned short f2bf(float f) {
  union { float f; unsigned int i; } c;
  c.f = f;
  const unsigned int r = c.i + 0x7fffu + ((c.i >> 16) & 1u);
  return (unsigned short)(r >> 16);
}

__device__ __forceinline__ unsigned short f2bf_hw(float f) {
  __hip_bfloat16 b = __float2bfloat16(f);
  return *reinterpret_cast<unsigned short*>(&b);
}

__device__ __forceinline__ bf16x8 cvt8(float4 lo, float4 hi) {
  union { bf16x8 v; unsigned short u[8]; } au;
  au.u[0] = f2bf_hw(lo.x); au.u[1] = f2bf_hw(lo.y);
  au.u[2] = f2bf_hw(lo.z); au.u[3] = f2bf_hw(lo.w);
  au.u[4] = f2bf_hw(hi.x); au.u[5] = f2bf_hw(hi.y);
  au.u[6] = f2bf_hw(hi.z); au.u[7] = f2bf_hw(hi.w);
  return au.v;
}

// ---------------------------------------------------------------------------
// Kernel 0: build FRAGMENT-MAJOR weights (unchanged since round 11).
// Wt2[((kt*12 + ni)*64 + lane)*8 + j] = W_sel[k][h]:
//   n = ni*16 + (lane&15), k = kt*32 + (lane>>4)*8 + j.
// ---------------------------------------------------------------------------
__global__ __launch_bounds__(256) void w_prep_kernel(
    const float* __restrict__ Wq,
    const float* __restrict__ Wk,
    const float* __restrict__ Wv,
    unsigned short* __restrict__ Wt2) {
  const int o = blockIdx.x * 256 + threadIdx.x;
  if (o >= WT_ELEMS) return;
  const int j = o & 7;
  const int lane = (o >> 3) & 63;
  const int fi = o >> 9;  // kt*12 + ni
  const int ni = fi % 12;
  const int kt = fi / 12;
  const int n = ni * 16 + (lane & 15);
  const int k = kt * 32 + ((lane >> 4) << 3) + j;
  const float* W = (n < 64) ? Wq : (n < 128) ? Wk : Wv;
  Wt2[o] = f2bf(W[k * NH + (n & 63)]);
}

// ---------------------------------------------------------------------------
// Kernel 1 (final = round 14, best measured 41.1 us): fused proj+attn,
// 16 waves/block (4/SIMD TLP), W fragment-major resident in LDS, x
// direct-to-reg 3-deep named register pipeline, no k-loop barriers.
//
// Campaign summary (rounds 7-16): eight structurally independent proj
// designs spanning VMEM staging instrument, barrier structure, DRAM page
// locality, TLP, LDS traffic, and pipeline depth land at 41-45 us (the
// two with duplicated x-loads: 49-54). No counter saturates; this is the
// empirical floor for the fused one-block-per-batch shape on MI355X.
//
// Wave->q-tile map: pandiagonal magic square (nibble-packed constant):
// every consecutive-4 AND stride-4 group of waves sums to 30 -> causal
// work balanced per SIMD under either wave->SIMD convention.
// Attn: 16-row q-tiles, 32-row K-blocks, parity diagonal mask.
// LDS reuse after proj: Kls 32K | Vtls 32K | Qls 32K | Pls 16x640B.
// mfma_f32_16x16x32_bf16 layouts (HW-verified round 2):
//   A/B: k = (l>>4)*8+j contiguous;  D: n = l&15, m = (l>>4)*4 + r.
// ---------------------------------------------------------------------------
__global__ __launch_bounds__(1024, 4) void fused_qkv_attn_kernel(
    const float* __restrict__ x,
    const unsigned short* __restrict__ Wt2,
    float* __restrict__ out) {
  __shared__ __align__(16) unsigned char lds[147456];

  const int tid = threadIdx.x;
  const int w = tid >> 6;  // 0..15
  const int lane = tid & 63;
  const int l15 = lane & 15;
  const int lg = lane >> 4;
  const int b = blockIdx.x;
  const int row0 = b * NT;
  // qt = magic[w]: nibble-packed pandiagonal magic square of 0..15.
  const int qt =
      (int)((0x583E2F49C1A7B6D0ull >> (w << 2)) & 15ull);
  const int wbase = qt * 16;  // wave's 16 q-rows (block-local)

  f32x4 acc[12];
#pragma unroll
  for (int ni = 0; ni < 12; ++ni)
#pragma unroll
    for (int r = 0; r < 4; ++r) acc[ni][r] = 0.f;

  // ---- stage ALL of W into LDS (9 x 16B DMA per thread, linear) ----
#pragma unroll
  for (int i = 0; i < 9; ++i) {
    const int idx = i * 1024 + tid;  // 16B chunk index, 9216 total
    __builtin_amdgcn_global_load_lds(
        (const __attribute__((address_space(1))) void*)(Wt2 + idx * 8),
        (__attribute__((address_space(3))) void*)(lds + idx * 16), 16, 0, 0);
  }

  // ---- A-pipeline prologue: issue tiles 0,1,2 into named sets ----
  const float* xa0 = x + (size_t)(row0 + wbase + l15) * NC + lg * 8;

  float4 aA0, aA1, aB0, aB1, aC0, aC1;

#define LOADA(S, KT)                                                          \
  do {                                                                        \
    a##S##0 = *reinterpret_cast<const float4*>(xa0 + (KT)*32);                \
    a##S##1 = *reinterpret_cast<const float4*>(xa0 + (KT)*32 + 4);            \
  } while (0)

  LOADA(A, 0);
  LOADA(B, 1);
  LOADA(C, 2);

  // Drain everything once (prologue only): guarantees the W image is
  // resident for every wave before the barrier, regardless of issue order.
  asm volatile("s_waitcnt vmcnt(0)" ::: "memory");
  __builtin_amdgcn_s_barrier();

  // ---- proj loop: consume set, refill 3 ahead; W from LDS ----
  const unsigned short* Wl =
      reinterpret_cast<const unsigned short*>(lds) + lane * 8;

#define STEP(S, KT)                                                           \
  do {                                                                        \
    const bf16x8 afr = cvt8(a##S##0, a##S##1);                                \
    if ((KT) + 3 < 12) LOADA(S, (KT) + 3);                                    \
    _Pragma("unroll") for (int ni = 0; ni < 12; ++ni) {                       \
      const bf16x8 bfr = *reinterpret_cast<const bf16x8*>(                    \
          Wl + (size_t)((KT)*12 + ni) * 512);                                 \
      acc[ni] = __builtin_amdgcn_mfma_f32_16x16x32_bf16(                      \
          afr, bfr, acc[ni], 0, 0, 0);                                        \
    }                                                                         \
  } while (0)

  STEP(A, 0);  STEP(B, 1);  STEP(C, 2);
  STEP(A, 3);  STEP(B, 4);  STEP(C, 5);
  STEP(A, 6);  STEP(B, 7);  STEP(C, 8);
  STEP(A, 9);  STEP(B, 10); STEP(C, 11);

  // All waves done reading the W image before overwriting LDS with K/V/Q.
  __syncthreads();

  // ---- epilogue: scatter acc into attention LDS layouts (bf16) ----
  unsigned short* Kls = reinterpret_cast<unsigned short*>(lds);           // 32K
  unsigned short* Vtls = reinterpret_cast<unsigned short*>(lds + 32768);  // 32K
  unsigned short* Qls = reinterpret_cast<unsigned short*>(lds + 65536);   // 32K
  unsigned short* Pls = reinterpret_cast<unsigned short*>(lds + 98304);   // 20K

#pragma unroll
  for (int ni = 0; ni < 12; ++ni) {
    const int n = ni * 16 + l15;
#pragma unroll
    for (int r = 0; r < 4; ++r) {
      const int srow = wbase + lg * 4 + r;
      const unsigned short val = f2bf_hw(acc[ni][r]);
      if (ni < 4) {
        Qls[srow * 64 + (n ^ ((srow & 7) << 3))] = val;
      } else if (ni < 8) {
        const int h = n - 64;
        Kls[srow * 64 + (h ^ ((srow & 7) << 3))] = val;
      } else {
        const int h = n - 128;
        Vtls[h * 256 + (srow ^ ((h & 7) << 3))] = val;
      }
    }
  }
  __syncthreads();

  // ---- attention phase (flash, per-wave independent, 16-row q-tile) ----
  bf16x8 a_q[2];
#pragma unroll
  for (int ks = 0; ks < 2; ++ks) {
    const int srow = wbase + l15;
    a_q[ks] = *reinterpret_cast<const bf16x8*>(
        Qls + srow * 64 + ((ks * 32 + lg * 8) ^ ((srow & 7) << 3)));
  }

  f32x4 o[4];
  float mrun[4], lrun[4];
#pragma unroll
  for (int r = 0; r < 4; ++r) {
    mrun[r] = -3.0e38f;
    lrun[r] = 0.f;
#pragma unroll
    for (int hi = 0; hi < 4; ++hi) o[hi][r] = 0.f;
  }

  unsigned short* Pw = Pls + w * 640;  // per-wave [16][40]
  const int njmax = qt >> 1;

  for (int j = 0; j <= njmax; ++j) {
    f32x4 s_acc[2];
#pragma unroll
    for (int si = 0; si < 2; ++si)
#pragma unroll
      for (int r = 0; r < 4; ++r) s_acc[si][r] = 0.f;

#pragma unroll
    for (int ks = 0; ks < 2; ++ks) {
      bf16x8 bk[2];
#pragma unroll
      for (int si = 0; si < 2; ++si) {
        const int srow = j * 32 + si * 16 + l15;
        const int kel = ks * 32 + lg * 8;
        bk[si] = *reinterpret_cast<const bf16x8*>(
            Kls + srow * 64 + (kel ^ ((srow & 7) << 3)));
      }
#pragma unroll
      for (int si = 0; si < 2; ++si)
        s_acc[si] = __builtin_amdgcn_mfma_f32_16x16x32_bf16(
            a_q[ks], bk[si], s_acc[si], 0, 0, 0);
    }

    const bool dlast = (j == njmax);
#pragma unroll
    for (int r = 0; r < 4; ++r) {
      const int mloc = lg * 4 + r;
      float v0 = s_acc[0][r] * 0.125f;
      float v1 = s_acc[1][r] * 0.125f;
      if (dlast) {
        if ((qt & 1) == 0) {
          if (l15 > mloc) v0 = -3.0e38f;
          v1 = -3.0e38f;  // whole upper half-block is future
        } else {
          if (l15 > mloc) v1 = -3.0e38f;
        }
      }
      float pm = fmaxf(v0, v1);
      pm = fmaxf(pm, __shfl_xor(pm, 1, 16));
      pm = fmaxf(pm, __shfl_xor(pm, 2, 16));
      pm = fmaxf(pm, __shfl_xor(pm, 4, 16));
      pm = fmaxf(pm, __shfl_xor(pm, 8, 16));
      const float mnew = fmaxf(mrun[r], pm);
      const float alpha = __expf(mrun[r] - mnew);
      mrun[r] = mnew;
      const float p0 = __expf(v0 - mnew);
      const float p1 = __expf(v1 - mnew);
      float ps = p0 + p1;
      ps += __shfl_xor(ps, 1, 16);
      ps += __shfl_xor(ps, 2, 16);
      ps += __shfl_xor(ps, 4, 16);
      ps += __shfl_xor(ps, 8, 16);
      lrun[r] = lrun[r] * alpha + ps;
#pragma unroll
      for (int hi = 0; hi < 4; ++hi) o[hi][r] *= alpha;
      Pw[mloc * 40 + l15] = f2bf(p0);
      Pw[mloc * 40 + 16 + l15] = f2bf(p1);
    }

    const bf16x8 pa =
        *reinterpret_cast<const bf16x8*>(Pw + l15 * 40 + lg * 8);
#pragma unroll
    for (int hi = 0; hi < 4; ++hi) {
      const int h = hi * 16 + l15;
      const int sel = j * 32 + lg * 8;
      const bf16x8 bv = *reinterpret_cast<const bf16x8*>(
          Vtls + h * 256 + (sel ^ ((h & 7) << 3)));
      o[hi] = __builtin_amdgcn_mfma_f32_16x16x32_bf16(pa, bv, o[hi], 0, 0, 0);
    }
  }

  // ---- out store ----
  float* og = out + ((size_t)b * NT + wbase) * NH;
#pragma unroll
  for (int r = 0; r < 4; ++r) {
    const float inv = 1.f / lrun[r];
    const int m = lg * 4 + r;
#pragma unroll
    for (int hi = 0; hi < 4; ++hi)
      og[m * 64 + hi * 16 + l15] = o[hi][r] * inv;
  }
}

// ---------------------------------------------------------------------------
extern "C" void kernel_launch(void* const* d_in, const int* in_sizes, int n_in,
                              void* d_out, int out_size, void* d_ws,
                              size_t ws_size, hipStream_t stream) {
  const float* x  = (const float*)d_in[0];
  const float* Wq = (const float*)d_in[1];
  const float* Wk = (const float*)d_in[2];
  const float* Wv = (const float*)d_in[3];
  unsigned short* Wt2 = (unsigned short*)d_ws;  // 147 KB, fragment-major
  float* out = (float*)d_out;

  w_prep_kernel<<<dim3((WT_ELEMS + 255) / 256), dim3(256), 0, stream>>>(
      Wq, Wk, Wv, Wt2);
  fused_qkv_attn_kernel<<<dim3(NB), dim3(1024), 0, stream>>>(x, Wt2, out);
}